// Round 1
// baseline (398.738 us; speedup 1.0000x reference)
//
#include <hip/hip_runtime.h>
#include <cstddef>

#define Bn 128
#define Pn 8732
#define Cn 21
#define On 16

__device__ __forceinline__ void argmax_combine(float& v, int& p, float v2, int p2) {
  if (v2 > v || (v2 == v && p2 < p)) { v = v2; p = p2; }
}

// ---------------------------------------------------------------------------
// Kernel 1: SSD matching. One block per image. Produces per-prior packed byte:
//   bits 0..3 = bti (matched truth index), bit 4 = pos flag.
// Exactly replicates: bto/bti (first-max over truths), best_prior_idx
// (first-max over priors), bto[bp[j]]=2.0, sequential bti[bp[j]]=j (last j wins).
// ---------------------------------------------------------------------------
__global__ __launch_bounds__(256) void match_kernel(
    const float* __restrict__ dbox, const float* __restrict__ targets,
    unsigned char* __restrict__ match) {
  const int b = blockIdx.x;
  const int tid = threadIdx.x;
  __shared__ float s_t[On * 5];
  __shared__ float s_area[On];
  __shared__ int s_bp[On];
  __shared__ float s_wv[On][4];
  __shared__ int s_wp[On][4];

  if (tid < On * 5) s_t[tid] = targets[(size_t)b * On * 5 + tid];
  __syncthreads();
  if (tid < On)
    s_area[tid] = (s_t[tid*5+2] - s_t[tid*5+0]) * (s_t[tid*5+3] - s_t[tid*5+1]);
  __syncthreads();

  // Pass 1: per-truth argmax over priors (first occurrence of max).
  float bestv[On]; int bestp[On];
  #pragma unroll
  for (int j = 0; j < On; j++) { bestv[j] = -1.0f; bestp[j] = 0x7fffffff; }

  for (int p = tid; p < Pn; p += 256) {
    float4 d = ((const float4*)dbox)[p];
    float px1 = d.x - d.z * 0.5f, py1 = d.y - d.w * 0.5f;
    float px2 = d.x + d.z * 0.5f, py2 = d.y + d.w * 0.5f;
    float ap = d.z * d.w;
    #pragma unroll
    for (int j = 0; j < On; j++) {
      float lx = fmaxf(s_t[j*5+0], px1);
      float ly = fmaxf(s_t[j*5+1], py1);
      float rx = fminf(s_t[j*5+2], px2);
      float ry = fminf(s_t[j*5+3], py2);
      float w = fmaxf(rx - lx, 0.0f), h = fmaxf(ry - ly, 0.0f);
      float inter = w * h;
      float ov = inter / (s_area[j] + ap - inter);
      if (ov > bestv[j]) { bestv[j] = ov; bestp[j] = p; }  // strict > keeps smallest p in subset
    }
  }

  #pragma unroll
  for (int j = 0; j < On; j++) {
    float v = bestv[j]; int p = bestp[j];
    #pragma unroll
    for (int off = 32; off; off >>= 1) {
      float v2 = __shfl_down(v, off);
      int p2 = __shfl_down(p, off);
      argmax_combine(v, p, v2, p2);
    }
    if ((tid & 63) == 0) { s_wv[j][tid >> 6] = v; s_wp[j][tid >> 6] = p; }
  }
  __syncthreads();
  if (tid < On) {
    float v = s_wv[tid][0]; int p = s_wp[tid][0];
    #pragma unroll
    for (int w = 1; w < 4; w++) argmax_combine(v, p, s_wv[tid][w], s_wp[tid][w]);
    s_bp[tid] = p;
  }
  __syncthreads();

  // Pass 2: per-prior best truth (first max over j), apply forced matches.
  for (int p = tid; p < Pn; p += 256) {
    float4 d = ((const float4*)dbox)[p];
    float px1 = d.x - d.z * 0.5f, py1 = d.y - d.w * 0.5f;
    float px2 = d.x + d.z * 0.5f, py2 = d.y + d.w * 0.5f;
    float ap = d.z * d.w;
    float mv = -1.0f; int mj = 0;
    #pragma unroll
    for (int j = 0; j < On; j++) {
      float lx = fmaxf(s_t[j*5+0], px1);
      float ly = fmaxf(s_t[j*5+1], py1);
      float rx = fminf(s_t[j*5+2], px2);
      float ry = fminf(s_t[j*5+3], py2);
      float w = fmaxf(rx - lx, 0.0f), h = fmaxf(ry - ly, 0.0f);
      float inter = w * h;
      float ov = inter / (s_area[j] + ap - inter);
      if (ov > mv) { mv = ov; mj = j; }  // strict > => first max (jnp.argmax axis=0)
    }
    int forced = -1;
    #pragma unroll
    for (int j = 0; j < On; j++) if (s_bp[j] == p) forced = j;  // last j wins
    int bti, pos;
    if (forced >= 0) { bti = forced; pos = 1; }                 // bto forced to 2.0 >= 0.5
    else { bti = mj; pos = (mv >= 0.5f) ? 1 : 0; }
    match[(size_t)b * Pn + p] = (unsigned char)(bti | (pos << 4));
  }
}

// ---------------------------------------------------------------------------
// Kernel 2: per-prior CE (log-softmax) + loc smooth-L1 for positives.
// Writes ce_neg[B][P]; atomically accumulates loss_l, pos-CE, num_pos.
// ---------------------------------------------------------------------------
__global__ __launch_bounds__(256) void loss_kernel(
    const float* __restrict__ loc_data, const float* __restrict__ conf_data,
    const float* __restrict__ dbox, const float* __restrict__ targets,
    const unsigned char* __restrict__ match,
    float* __restrict__ ce_neg, int* __restrict__ num_pos,
    float* __restrict__ acc) {
  const int b = blockIdx.y;
  const int tile = blockIdx.x * 256;
  const int tid = threadIdx.x;
  const int rows = min(256, Pn - tile);
  __shared__ float lds[256 * Cn];
  __shared__ float redf[8];
  __shared__ int redi[4];

  const float* src = conf_data + ((size_t)b * Pn + tile) * Cn;
  if (rows == 256) {
    // base is 16B aligned: (b*Pn + tile)*Cn*4 with Pn*Cn and 256*Cn both %4==0
    const float4* s4 = (const float4*)src;
    float4* l4 = (float4*)lds;
    for (int i = tid; i < 256 * Cn / 4; i += 256) l4[i] = s4[i];
  } else {
    for (int i = tid; i < rows * Cn; i += 256) lds[i] = src[i];
  }
  __syncthreads();

  float my_ce_pos = 0.0f, my_loc = 0.0f; int my_pos = 0;
  const int p = tile + tid;
  if (tid < rows) {
    const float* x = lds + tid * Cn;
    float m = x[0];
    #pragma unroll
    for (int i = 1; i < Cn; i++) m = fmaxf(m, x[i]);
    float s = 0.0f;
    #pragma unroll
    for (int i = 0; i < Cn; i++) s += expf(x[i] - m);
    float lse = m + logf(s);

    unsigned char mb = match[(size_t)b * Pn + p];
    int pos = (mb >> 4) & 1;
    int bti = mb & 15;
    const float* t = targets + ((size_t)b * On + bti) * 5;
    int c = pos ? ((int)t[4] + 1) : 0;
    float ce = lse - x[c];
    ce_neg[(size_t)b * Pn + p] = pos ? 0.0f : ce;

    if (pos) {
      my_ce_pos = ce;
      my_pos = 1;
      float4 d = ((const float4*)dbox)[p];
      float mx1 = t[0], my1 = t[1], mx2 = t[2], my2 = t[3];
      float g0 = ((mx1 + mx2) * 0.5f - d.x) / (0.1f * d.z);
      float g1 = ((my1 + my2) * 0.5f - d.y) / (0.1f * d.w);
      float g2 = logf((mx2 - mx1) / d.z) / 0.2f;
      float g3 = logf((my2 - my1) / d.w) / 0.2f;
      float4 ld = ((const float4*)loc_data)[(size_t)b * Pn + p];
      float g[4] = {g0, g1, g2, g3};
      float l[4] = {ld.x, ld.y, ld.z, ld.w};
      #pragma unroll
      for (int i = 0; i < 4; i++) {
        float ad = fabsf(l[i] - g[i]);
        my_loc += (ad < 1.0f) ? 0.5f * ad * ad : ad - 0.5f;
      }
    }
  }

  #pragma unroll
  for (int off = 32; off; off >>= 1) {
    my_ce_pos += __shfl_down(my_ce_pos, off);
    my_loc    += __shfl_down(my_loc, off);
    my_pos    += __shfl_down(my_pos, off);
  }
  const int wave = tid >> 6;
  if ((tid & 63) == 0) { redf[wave] = my_ce_pos; redf[4 + wave] = my_loc; redi[wave] = my_pos; }
  __syncthreads();
  if (tid == 0) {
    float ce_s  = redf[0] + redf[1] + redf[2] + redf[3];
    float loc_s = redf[4] + redf[5] + redf[6] + redf[7];
    int pos_s   = redi[0] + redi[1] + redi[2] + redi[3];
    atomicAdd(&acc[0], loc_s);
    atomicAdd(&acc[1], ce_s);
    atomicAdd(&num_pos[b], pos_s);
  }
}

// ---------------------------------------------------------------------------
// Kernel 3: per-image hard-negative top-k sum via exact MSB radix select.
// ce_neg >= 0 so float ordering == uint ordering of the bit patterns.
// Replicates stable double-argsort selection: sum(v>T) + (k - cnt_gt)*T.
// ---------------------------------------------------------------------------
__global__ __launch_bounds__(256) void select_kernel(
    const float* __restrict__ ce_neg, const int* __restrict__ num_pos,
    float* __restrict__ acc) {
  const int b = blockIdx.x;
  const int tid = threadIdx.x;
  const int k = min(num_pos[b] * 3, Pn);
  const unsigned* v = (const unsigned*)(ce_neg + (size_t)b * Pn);
  __shared__ unsigned hist[256];
  __shared__ unsigned s_prefix;
  __shared__ int s_kk;
  __shared__ float rs[4];
  __shared__ int rc[4];

  unsigned prefix = 0, mask = 0;
  int kk = k;
  if (k > 0) {
    for (int shift = 24; shift >= 0; shift -= 8) {
      hist[tid] = 0;
      __syncthreads();
      for (int i = tid; i < Pn; i += 256) {
        unsigned u = v[i];
        if ((u & mask) == prefix) atomicAdd(&hist[(u >> shift) & 255u], 1u);
      }
      __syncthreads();
      if (tid == 0) {
        int cum = 0, chosen = 0;
        for (int bin = 255; bin >= 0; bin--) {
          int c = (int)hist[bin];
          if (cum + c >= kk) { chosen = bin; break; }
          cum += c;
        }
        s_prefix = prefix | ((unsigned)chosen << shift);
        s_kk = kk - cum;
      }
      __syncthreads();
      prefix = s_prefix; kk = s_kk;
      mask |= 255u << shift;
    }
  }
  float T = __uint_as_float(prefix);

  float sum_gt = 0.0f; int cnt_gt = 0;
  if (k > 0) {
    const float* vf = ce_neg + (size_t)b * Pn;
    for (int i = tid; i < Pn; i += 256) {
      float x = vf[i];
      if (x > T) { sum_gt += x; cnt_gt++; }
    }
  }
  #pragma unroll
  for (int off = 32; off; off >>= 1) {
    sum_gt += __shfl_down(sum_gt, off);
    cnt_gt += __shfl_down(cnt_gt, off);
  }
  const int wave = tid >> 6;
  if ((tid & 63) == 0) { rs[wave] = sum_gt; rc[wave] = cnt_gt; }
  __syncthreads();
  if (tid == 0) {
    float s = rs[0] + rs[1] + rs[2] + rs[3];
    int c = rc[0] + rc[1] + rc[2] + rc[3];
    float sel = s + (float)(k - c) * T;
    atomicAdd(&acc[2], sel);
  }
}

__global__ void finalize_kernel(const int* __restrict__ num_pos,
                                const float* __restrict__ acc,
                                float* __restrict__ out) {
  if (threadIdx.x == 0 && blockIdx.x == 0) {
    int N = 0;
    for (int b = 0; b < Bn; b++) N += num_pos[b];
    float fN = (float)N;
    out[0] = acc[0] / fN;
    out[1] = (acc[1] + acc[2]) / fN;
  }
}

extern "C" void kernel_launch(void* const* d_in, const int* in_sizes, int n_in,
                              void* d_out, int out_size, void* d_ws, size_t ws_size,
                              hipStream_t stream) {
  const float* loc_data  = (const float*)d_in[0];
  const float* conf_data = (const float*)d_in[1];
  const float* dbox      = (const float*)d_in[2];
  const float* targets   = (const float*)d_in[3];
  float* out = (float*)d_out;

  char* ws = (char*)d_ws;
  float* ce_neg = (float*)ws;                                      // B*P floats
  unsigned char* match = (unsigned char*)(ws + (size_t)Bn * Pn * 4); // B*P bytes
  int* num_pos = (int*)(ws + (size_t)Bn * Pn * 5);                 // B ints
  float* acc = (float*)(ws + (size_t)Bn * Pn * 5 + Bn * 4);        // 4 floats

  hipMemsetAsync(num_pos, 0, Bn * 4 + 16, stream);

  match_kernel<<<Bn, 256, 0, stream>>>(dbox, targets, match);
  dim3 gB((Pn + 255) / 256, Bn);
  loss_kernel<<<gB, 256, 0, stream>>>(loc_data, conf_data, dbox, targets, match,
                                      ce_neg, num_pos, acc);
  select_kernel<<<Bn, 256, 0, stream>>>(ce_neg, num_pos, acc);
  finalize_kernel<<<1, 64, 0, stream>>>(num_pos, acc, out);
}